// Round 13
// baseline (161.078 us; speedup 1.0000x reference)
//
#include <hip/hip_runtime.h>
#include <hip/hip_bf16.h>

// N=8192, D_IN=128, H=64, C=40, E=262144, TAU=0.25, T=4 -> 16 steps.
constexpr int N_   = 8192;
constexpr int DIN_ = 128;
constexpr int H_   = 64;
constexpr int C_   = 40;
constexpr int STEPS_ = 16;
constexpr int CAP_ = 128;            // raw bucket capacity (max raw deg ~65)
#define TAU_ 0.25f

typedef float    f32x4 __attribute__((ext_vector_type(4)));
typedef unsigned int u32x4 __attribute__((ext_vector_type(4)));
typedef _Float16 f16x4 __attribute__((ext_vector_type(4)));

// pack (v, w) -> 4B: high 19 bits = fp32 w RNE-rounded to 10-bit mantissa,
// low 13 bits = v. w >= 0 always; w=0 packs/decodes exactly (packvw(0,0)==0).
__device__ __forceinline__ unsigned int packvw(int v, float w)
{
    unsigned int u = __float_as_uint(w);
    u += 0x0FFFu + ((u >> 13) & 1u);     // round-to-nearest-even at bit 13
    u &= 0xFFFFE000u;
    return u | (unsigned int)v;
}

// ---------------- fused front-end: enc + kq + z0 = x0 @ dec_w ---------------
__global__ __launch_bounds__(256) void front_k(const float* __restrict__ xin,
    const float* __restrict__ ew, const float* __restrict__ eb,
    const float* __restrict__ wk, const float* __restrict__ kb,
    const float* __restrict__ wq, const float* __restrict__ qb,
    const float* __restrict__ dw,
    float* __restrict__ kx, float* __restrict__ qx,
    float* __restrict__ z0, _Float16* __restrict__ zh0)
{
    __shared__ float xs[16][64];                 // 4 waves x 4 rows
    int wloc = threadIdx.x >> 6;
    int lane = threadIdx.x & 63;
    int r0   = (blockIdx.x * 4 + wloc) * 4;

    const float* xr = xin + (size_t)r0 * DIN_;
    float bv = eb[lane];
    float a0 = bv, a1 = bv, a2 = bv, a3 = bv;
    for (int k = 0; k < DIN_; ++k) {
        float wv = ew[k * H_ + lane];
        a0 = fmaf(xr[k],            wv, a0);
        a1 = fmaf(xr[DIN_ + k],     wv, a1);
        a2 = fmaf(xr[2 * DIN_ + k], wv, a2);
        a3 = fmaf(xr[3 * DIN_ + k], wv, a3);
    }
    float* xls = &xs[wloc * 4][0];
    xls[lane] = a0; xls[64 + lane] = a1; xls[128 + lane] = a2; xls[192 + lane] = a3;

    float kbv = kb[lane], qbv = qb[lane];
    float ak0 = kbv, ak1 = kbv, ak2 = kbv, ak3 = kbv;
    float aq0 = qbv, aq1 = qbv, aq2 = qbv, aq3 = qbv;
    for (int k = 0; k < H_; ++k) {
        float wkv = wk[k * H_ + lane];
        float wqv = wq[k * H_ + lane];
        float x0v = xls[k], x1v = xls[64 + k], x2v = xls[128 + k], x3v = xls[192 + k];
        ak0 = fmaf(x0v, wkv, ak0);  aq0 = fmaf(x0v, wqv, aq0);
        ak1 = fmaf(x1v, wkv, ak1);  aq1 = fmaf(x1v, wqv, aq1);
        ak2 = fmaf(x2v, wkv, ak2);  aq2 = fmaf(x2v, wqv, aq2);
        ak3 = fmaf(x3v, wkv, ak3);  aq3 = fmaf(x3v, wqv, aq3);
    }
    float* ok = kx + (size_t)r0 * H_ + lane;
    float* oq = qx + (size_t)r0 * H_ + lane;
    ok[0] = ak0; ok[H_] = ak1; ok[2 * H_] = ak2; ok[3 * H_] = ak3;
    oq[0] = aq0; oq[H_] = aq1; oq[2 * H_] = aq2; oq[3 * H_] = aq3;

    if (lane < C_) {
        float z0a = 0.f, z1a = 0.f, z2a = 0.f, z3a = 0.f;
        for (int k = 0; k < H_; ++k) {
            float dv = dw[k * C_ + lane];
            z0a = fmaf(xls[k],       dv, z0a);
            z1a = fmaf(xls[64 + k],  dv, z1a);
            z2a = fmaf(xls[128 + k], dv, z2a);
            z3a = fmaf(xls[192 + k], dv, z3a);
        }
        z0[(size_t)r0 * C_ + lane]       = z0a;
        z0[(size_t)(r0 + 1) * C_ + lane] = z1a;
        z0[(size_t)(r0 + 2) * C_ + lane] = z2a;
        z0[(size_t)(r0 + 3) * C_ + lane] = z3a;
        zh0[(size_t)r0 * C_ + lane]       = (_Float16)z0a;
        zh0[(size_t)(r0 + 1) * C_ + lane] = (_Float16)z1a;
        zh0[(size_t)(r0 + 2) * C_ + lane] = (_Float16)z2a;
        zh0[(size_t)(r0 + 3) * C_ + lane] = (_Float16)z3a;
    }
}

// ---------------- edge scoring straight into padded row buckets -------------
__global__ __launch_bounds__(256) void score_place_k(const int2* __restrict__ edges,
    const float* __restrict__ kx, const float* __restrict__ qx,
    int* __restrict__ fill, int2* __restrict__ bvw, int E)
{
    int t  = blockIdx.x * 256 + threadIdx.x;
    int eg = t >> 3;
    int sl = t & 7;
    if (eg >= E) return;
    int2 uv = edges[eg];
    const float4* kr = (const float4*)(kx + (size_t)uv.x * H_);
    const float4* qr = (const float4*)(qx + (size_t)uv.y * H_);
    float4 a0 = kr[sl], a1 = kr[sl + 8];
    float4 b0 = qr[sl], b1 = qr[sl + 8];
    float d = a0.x * b0.x + a0.y * b0.y + a0.z * b0.z + a0.w * b0.w
            + a1.x * b1.x + a1.y * b1.y + a1.z * b1.z + a1.w * b1.w;
    d += __shfl_xor(d, 1);
    d += __shfl_xor(d, 2);
    d += __shfl_xor(d, 4);
    if (sl == 0) {
        float w = expf(d * (1.0f / (float)H_));
        int pos = atomicAdd(&fill[uv.x], 1);
        if (pos < CAP_)
            bvw[(size_t)uv.x * CAP_ + pos] = make_int2(uv.y, __float_as_int(w));
    }
}

// ---------------- compact-offset scan (single block) ------------------------
// rinfo[row] = (element offset of row's compact segment, #16-edge chunks).
// Padded counts are multiples of 16 -> segments are 64B line-aligned.
__global__ __launch_bounds__(256) void scan_k(const int* __restrict__ fill,
    int2* __restrict__ rinfo)
{
    __shared__ int partial[256];
    int t = threadIdx.x;
    const int chunk = N_ / 256;        // 32 rows per thread
    int base = t * chunk;
    int s = 0;
    for (int i = 0; i < chunk; ++i) {
        int f = fill[base + i];
        if (f > CAP_) f = CAP_;
        s += (f + 15) & ~15;
    }
    partial[t] = s;
    __syncthreads();
    if (t == 0) {
        int run = 0;
        for (int i = 0; i < 256; ++i) { int tmp = partial[i]; partial[i] = run; run += tmp; }
    }
    __syncthreads();
    int run = partial[t];
    for (int i = 0; i < chunk; ++i) {
        int f = fill[base + i];
        if (f > CAP_) f = CAP_;
        int padded = (f + 15) & ~15;
        rinfo[base + i] = make_int2(run, padded >> 4);
        run += padded;
    }
}

// ---------------- per-row dedup + normalize + pack -> COMPACT pw ------------
// Wave per row; lane owns slots {lane, lane+64} of the raw bucket. LDS bitmap
// dedup (any-winner exact). Writes packed 4B (v,w) at the compact offset with
// the interleave permutation newp = (p&~15) | ((p&3)<<2) | ((p&15)>>2) so each
// stepz group's 4 packets are one contiguous 16B quad. Padding packs to 0.
__global__ __launch_bounds__(256) void dedup_k(const int* __restrict__ fill,
    const int2* __restrict__ rinfo, const int2* __restrict__ bvw,
    unsigned int* __restrict__ pw)
{
    __shared__ unsigned int bm[4][256];   // 8192 bits per wave
    int wv   = threadIdx.x >> 6;
    int lane = threadIdx.x & 63;
    int row  = blockIdx.x * 4 + wv;
    unsigned int* b = bm[wv];
    for (int i = lane; i < 256; i += 64) b[i] = 0;
    __syncthreads();
    int f = fill[row];
    if (f > CAP_) f = CAP_;
    int padded = (f + 15) & ~15;
    size_t src = (size_t)row * CAP_;
    size_t dst = (size_t)rinfo[row].x;
    int2 ea = make_int2(0, 0), eb = make_int2(0, 0);
    float wa = 0.f, wb = 0.f;
    if (lane < f) {
        ea = bvw[src + lane];
        unsigned int m = 1u << (ea.x & 31);
        unsigned int old = atomicOr(&b[ea.x >> 5], m);
        wa = (old & m) ? 0.0f : __int_as_float(ea.y);
    }
    if (64 + lane < f) {
        eb = bvw[src + 64 + lane];
        unsigned int m = 1u << (eb.x & 31);
        unsigned int old = atomicOr(&b[eb.x >> 5], m);
        wb = (old & m) ? 0.0f : __int_as_float(eb.y);
    }
    float wsum = wa + wb;
    #pragma unroll
    for (int off = 1; off < 64; off <<= 1) wsum += __shfl_xor(wsum, off);
    if (f == 0) return;
    float scale = TAU_ / wsum;
    int pa = lane;
    int na = (pa & ~15) | ((pa & 3) << 2) | ((pa & 15) >> 2);
    int pb = 64 + lane;
    int nb = (pb & ~15) | ((pb & 3) << 2) | ((pb & 15) >> 2);
    if (pa < padded) pw[dst + na] = packvw(ea.x, wa * scale);
    if (pb < padded) pw[dst + nb] = packvw(eb.x, wb * scale);
}

// ---------------- propagation step over z (N x 40) ----------------
// State z fp32 (exact diagonal + output); gathers read fp16 shadow zh.
// Wave = row; grp=L>>4, col4=L&15 (c<10 valid). Per chunk: one dwordx4 pw
// quad + 4 dwordx2 fp16 gathers + 16 fma. pw is compact (~1.2 MB) so the
// per-XCD step working set fits L2.
template <bool LAST>
__global__ __launch_bounds__(256) void stepz_k(const float* __restrict__ zin,
    const _Float16* __restrict__ zhin, float* __restrict__ zout,
    _Float16* __restrict__ zhout, const int2* __restrict__ rinfo,
    const unsigned int* __restrict__ pw, const float* __restrict__ db)
{
    int row  = (blockIdx.x * 256 + threadIdx.x) >> 6;
    int lane = threadIdx.x & 63;
    int grp  = lane >> 4;
    int col4 = lane & 15;
    int c9   = (col4 < 10) ? col4 : 9;
    int ch   = c9 << 2;                    // half-offset within row
    int2 ri  = rinfo[row];                 // (offset, nchunks) wave-uniform
    int ncv  = ri.y;
    const unsigned int* pwrow = pw + (size_t)ri.x + (grp << 2);
    f32x4 acc = {0.f, 0.f, 0.f, 0.f};
    u32x4 q = *(const u32x4*)pwrow;        // chunk 0 quad (unused if ncv==0)
    for (int c = 0; c < ncv; ++c) {
        f16x4 h0 = *(const f16x4*)(zhin + (size_t)(q[0] & 0x1FFFu) * C_ + ch);
        f16x4 h1 = *(const f16x4*)(zhin + (size_t)(q[1] & 0x1FFFu) * C_ + ch);
        f16x4 h2 = *(const f16x4*)(zhin + (size_t)(q[2] & 0x1FFFu) * C_ + ch);
        f16x4 h3 = *(const f16x4*)(zhin + (size_t)(q[3] & 0x1FFFu) * C_ + ch);
        int cn = (c + 1 < ncv) ? (c + 1) : c;            // branch-free lookahead
        u32x4 qn = *(const u32x4*)(pwrow + ((size_t)cn << 4));
        float w0 = __uint_as_float(q[0] & 0xFFFFE000u);
        float w1 = __uint_as_float(q[1] & 0xFFFFE000u);
        float w2 = __uint_as_float(q[2] & 0xFFFFE000u);
        float w3 = __uint_as_float(q[3] & 0xFFFFE000u);
        acc[0] = fmaf(w0, (float)h0[0], acc[0]); acc[1] = fmaf(w0, (float)h0[1], acc[1]);
        acc[2] = fmaf(w0, (float)h0[2], acc[2]); acc[3] = fmaf(w0, (float)h0[3], acc[3]);
        acc[0] = fmaf(w1, (float)h1[0], acc[0]); acc[1] = fmaf(w1, (float)h1[1], acc[1]);
        acc[2] = fmaf(w1, (float)h1[2], acc[2]); acc[3] = fmaf(w1, (float)h1[3], acc[3]);
        acc[0] = fmaf(w2, (float)h2[0], acc[0]); acc[1] = fmaf(w2, (float)h2[1], acc[1]);
        acc[2] = fmaf(w2, (float)h2[2], acc[2]); acc[3] = fmaf(w2, (float)h2[3], acc[3]);
        acc[0] = fmaf(w3, (float)h3[0], acc[0]); acc[1] = fmaf(w3, (float)h3[1], acc[1]);
        acc[2] = fmaf(w3, (float)h3[2], acc[2]); acc[3] = fmaf(w3, (float)h3[3], acc[3]);
        q = qn;
    }
    acc[0] += __shfl_xor(acc[0], 16); acc[1] += __shfl_xor(acc[1], 16);
    acc[2] += __shfl_xor(acc[2], 16); acc[3] += __shfl_xor(acc[3], 16);
    acc[0] += __shfl_xor(acc[0], 32); acc[1] += __shfl_xor(acc[1], 32);
    acc[2] += __shfl_xor(acc[2], 32); acc[3] += __shfl_xor(acc[3], 32);
    if (grp == 0 && col4 < 10) {
        f32x4 xr = *(const f32x4*)(zin + (size_t)row * C_ + (col4 << 2));
        f32x4 r;
        r[0] = fmaf(1.0f - TAU_, xr[0], acc[0]);
        r[1] = fmaf(1.0f - TAU_, xr[1], acc[1]);
        r[2] = fmaf(1.0f - TAU_, xr[2], acc[2]);
        r[3] = fmaf(1.0f - TAU_, xr[3], acc[3]);
        if (LAST) {
            f32x4 bb = *(const f32x4*)(db + (col4 << 2));
            r[0] += bb[0]; r[1] += bb[1]; r[2] += bb[2]; r[3] += bb[3];
        }
        *(f32x4*)(zout + (size_t)row * C_ + (col4 << 2)) = r;
        if (!LAST) {
            f16x4 rh;
            rh[0] = (_Float16)r[0]; rh[1] = (_Float16)r[1];
            rh[2] = (_Float16)r[2]; rh[3] = (_Float16)r[3];
            *(f16x4*)(zhout + (size_t)row * C_ + (col4 << 2)) = rh;
        }
    }
}

extern "C" void kernel_launch(void* const* d_in, const int* in_sizes, int n_in,
                              void* d_out, int out_size, void* d_ws, size_t ws_size,
                              hipStream_t stream)
{
    const float* x_in  = (const float*)d_in[0];
    const float* enc_w = (const float*)d_in[1];
    const float* enc_b = (const float*)d_in[2];
    const float* wk_w  = (const float*)d_in[3];
    const float* wk_b  = (const float*)d_in[4];
    const float* wq_w  = (const float*)d_in[5];
    const float* wq_b  = (const float*)d_in[6];
    const float* dec_w = (const float*)d_in[7];
    const float* dec_b = (const float*)d_in[8];
    const int2*  edges = (const int2*)d_in[9];
    const int E = in_sizes[9] / 2;   // 262144
    float* out = (float*)d_out;

    char* ws = (char*)d_ws;
    float*        za   = (float*)(ws + 0);                    // 1.31 MB (+pad)
    float*        zb   = (float*)(ws + (2u << 20));           // 1.31 MB (+pad)
    float*        kx   = (float*)(ws + (4u << 20));           // 2 MB
    float*        qx   = (float*)(ws + (6u << 20));           // 2 MB
    int2*         bvw  = (int2*) (ws + (8u << 20));           // 8 MB raw buckets
    unsigned int* pw   = (unsigned int*)(ws + (16u << 20));   // ~1.3 MB compact
    int*          fill = (int*)  (ws + (18u << 20));          // 32 KB
    int2*         rinfo= (int2*) (ws + (18u << 20) + (64u << 10)); // 64 KB
    _Float16*     zha  = (_Float16*)(ws + (19u << 20));       // 640 KB
    _Float16*     zhb  = (_Float16*)(ws + (20u << 20));       // 640 KB

    hipMemsetAsync(fill, 0, N_ * sizeof(int), stream);

    front_k<<<N_ / 16, 256, 0, stream>>>(x_in, enc_w, enc_b, wk_w, wk_b,
                                         wq_w, wq_b, dec_w, kx, qx, za, zha);
    score_place_k<<<(E * 8 + 255) / 256, 256, 0, stream>>>(edges, kx, qx, fill, bvw, E);
    scan_k<<<1, 256, 0, stream>>>(fill, rinfo);
    dedup_k<<<N_ / 4, 256, 0, stream>>>(fill, rinfo, bvw, pw);

    float*    zi  = za;
    _Float16* zhi = zha;
    for (int s = 0; s < STEPS_ - 1; ++s) {
        float*    zo  = (zi == za) ? zb : za;
        _Float16* zho = (zhi == zha) ? zhb : zha;
        stepz_k<false><<<N_ / 4, 256, 0, stream>>>(zi, zhi, zo, zho, rinfo, pw, dec_b);
        zi = zo; zhi = zho;
    }
    stepz_k<true><<<N_ / 4, 256, 0, stream>>>(zi, zhi, out, nullptr, rinfo, pw, dec_b);
}

// Round 14
// 152.874 us; speedup vs baseline: 1.0537x; 1.0537x over previous
//
#include <hip/hip_runtime.h>
#include <hip/hip_bf16.h>

// N=8192, D_IN=128, H=64, C=40, E=262144, TAU=0.25, T=4 -> 16 steps.
constexpr int N_   = 8192;
constexpr int DIN_ = 128;
constexpr int H_   = 64;
constexpr int C_   = 40;
constexpr int STEPS_ = 16;
constexpr int CAP_ = 128;            // row bucket capacity (max raw deg ~65)
#define TAU_ 0.25f

typedef float    f32x4 __attribute__((ext_vector_type(4)));
typedef unsigned int u32x4 __attribute__((ext_vector_type(4)));
typedef _Float16 f16x4 __attribute__((ext_vector_type(4)));

// pack (v, w) -> 4B: high 19 bits = fp32 w RNE-rounded to 10-bit mantissa,
// low 13 bits = v. w >= 0 always; w=0 packs/decodes exactly (packvw(0,0)==0).
__device__ __forceinline__ unsigned int packvw(int v, float w)
{
    unsigned int u = __float_as_uint(w);
    u += 0x0FFFu + ((u >> 13) & 1u);     // round-to-nearest-even at bit 13
    u &= 0xFFFFE000u;
    return u | (unsigned int)v;
}

// ---------------- fused front-end: enc + kq + z0 = x0 @ dec_w ---------------
__global__ __launch_bounds__(256) void front_k(const float* __restrict__ xin,
    const float* __restrict__ ew, const float* __restrict__ eb,
    const float* __restrict__ wk, const float* __restrict__ kb,
    const float* __restrict__ wq, const float* __restrict__ qb,
    const float* __restrict__ dw,
    float* __restrict__ kx, float* __restrict__ qx,
    float* __restrict__ z0, _Float16* __restrict__ zh0)
{
    __shared__ float xs[16][64];                 // 4 waves x 4 rows
    int wloc = threadIdx.x >> 6;
    int lane = threadIdx.x & 63;
    int r0   = (blockIdx.x * 4 + wloc) * 4;

    const float* xr = xin + (size_t)r0 * DIN_;
    float bv = eb[lane];
    float a0 = bv, a1 = bv, a2 = bv, a3 = bv;
    for (int k = 0; k < DIN_; ++k) {
        float wv = ew[k * H_ + lane];
        a0 = fmaf(xr[k],            wv, a0);
        a1 = fmaf(xr[DIN_ + k],     wv, a1);
        a2 = fmaf(xr[2 * DIN_ + k], wv, a2);
        a3 = fmaf(xr[3 * DIN_ + k], wv, a3);
    }
    float* xls = &xs[wloc * 4][0];
    xls[lane] = a0; xls[64 + lane] = a1; xls[128 + lane] = a2; xls[192 + lane] = a3;

    float kbv = kb[lane], qbv = qb[lane];
    float ak0 = kbv, ak1 = kbv, ak2 = kbv, ak3 = kbv;
    float aq0 = qbv, aq1 = qbv, aq2 = qbv, aq3 = qbv;
    for (int k = 0; k < H_; ++k) {
        float wkv = wk[k * H_ + lane];
        float wqv = wq[k * H_ + lane];
        float x0v = xls[k], x1v = xls[64 + k], x2v = xls[128 + k], x3v = xls[192 + k];
        ak0 = fmaf(x0v, wkv, ak0);  aq0 = fmaf(x0v, wqv, aq0);
        ak1 = fmaf(x1v, wkv, ak1);  aq1 = fmaf(x1v, wqv, aq1);
        ak2 = fmaf(x2v, wkv, ak2);  aq2 = fmaf(x2v, wqv, aq2);
        ak3 = fmaf(x3v, wkv, ak3);  aq3 = fmaf(x3v, wqv, aq3);
    }
    float* ok = kx + (size_t)r0 * H_ + lane;
    float* oq = qx + (size_t)r0 * H_ + lane;
    ok[0] = ak0; ok[H_] = ak1; ok[2 * H_] = ak2; ok[3 * H_] = ak3;
    oq[0] = aq0; oq[H_] = aq1; oq[2 * H_] = aq2; oq[3 * H_] = aq3;

    if (lane < C_) {
        float z0a = 0.f, z1a = 0.f, z2a = 0.f, z3a = 0.f;
        for (int k = 0; k < H_; ++k) {
            float dv = dw[k * C_ + lane];
            z0a = fmaf(xls[k],       dv, z0a);
            z1a = fmaf(xls[64 + k],  dv, z1a);
            z2a = fmaf(xls[128 + k], dv, z2a);
            z3a = fmaf(xls[192 + k], dv, z3a);
        }
        z0[(size_t)r0 * C_ + lane]       = z0a;
        z0[(size_t)(r0 + 1) * C_ + lane] = z1a;
        z0[(size_t)(r0 + 2) * C_ + lane] = z2a;
        z0[(size_t)(r0 + 3) * C_ + lane] = z3a;
        zh0[(size_t)r0 * C_ + lane]       = (_Float16)z0a;
        zh0[(size_t)(r0 + 1) * C_ + lane] = (_Float16)z1a;
        zh0[(size_t)(r0 + 2) * C_ + lane] = (_Float16)z2a;
        zh0[(size_t)(r0 + 3) * C_ + lane] = (_Float16)z3a;
    }
}

// ---------------- edge scoring straight into padded row buckets -------------
__global__ __launch_bounds__(256) void score_place_k(const int2* __restrict__ edges,
    const float* __restrict__ kx, const float* __restrict__ qx,
    int* __restrict__ fill, int2* __restrict__ bvw, int E)
{
    int t  = blockIdx.x * 256 + threadIdx.x;
    int eg = t >> 3;
    int sl = t & 7;
    if (eg >= E) return;
    int2 uv = edges[eg];
    const float4* kr = (const float4*)(kx + (size_t)uv.x * H_);
    const float4* qr = (const float4*)(qx + (size_t)uv.y * H_);
    float4 a0 = kr[sl], a1 = kr[sl + 8];
    float4 b0 = qr[sl], b1 = qr[sl + 8];
    float d = a0.x * b0.x + a0.y * b0.y + a0.z * b0.z + a0.w * b0.w
            + a1.x * b1.x + a1.y * b1.y + a1.z * b1.z + a1.w * b1.w;
    d += __shfl_xor(d, 1);
    d += __shfl_xor(d, 2);
    d += __shfl_xor(d, 4);
    if (sl == 0) {
        float w = expf(d * (1.0f / (float)H_));
        int pos = atomicAdd(&fill[uv.x], 1);
        if (pos < CAP_)
            bvw[(size_t)uv.x * CAP_ + pos] = make_int2(uv.y, __float_as_int(w));
    }
}

// ---------------- per-row dedup + normalize + pack (single pass) ------------
__global__ __launch_bounds__(256) void dedup_k(const int* __restrict__ fill,
    const int2* __restrict__ bvw, unsigned int* __restrict__ pw,
    int* __restrict__ nc)
{
    __shared__ unsigned int bm[4][256];   // 8192 bits per wave
    int wv   = threadIdx.x >> 6;
    int lane = threadIdx.x & 63;
    int row  = blockIdx.x * 4 + wv;
    unsigned int* b = bm[wv];
    for (int i = lane; i < 256; i += 64) b[i] = 0;
    __syncthreads();
    int f = fill[row];
    if (f > CAP_) f = CAP_;
    int padded = (f + 15) & ~15;
    size_t base = (size_t)row * CAP_;
    int2 ea = make_int2(0, 0), eb = make_int2(0, 0);
    float wa = 0.f, wb = 0.f;
    if (lane < f) {
        ea = bvw[base + lane];
        unsigned int m = 1u << (ea.x & 31);
        unsigned int old = atomicOr(&b[ea.x >> 5], m);
        wa = (old & m) ? 0.0f : __int_as_float(ea.y);
    }
    if (64 + lane < f) {
        eb = bvw[base + 64 + lane];
        unsigned int m = 1u << (eb.x & 31);
        unsigned int old = atomicOr(&b[eb.x >> 5], m);
        wb = (old & m) ? 0.0f : __int_as_float(eb.y);
    }
    float wsum = wa + wb;
    #pragma unroll
    for (int off = 1; off < 64; off <<= 1) wsum += __shfl_xor(wsum, off);
    if (lane == 0) nc[row] = padded >> 4;
    if (f == 0) return;
    float scale = TAU_ / wsum;
    // interleave permutation: newp = (p & ~15) | ((p & 3) << 2) | ((p & 15) >> 2)
    int pa = lane;
    int na = (pa & ~15) | ((pa & 3) << 2) | ((pa & 15) >> 2);
    int pb = 64 + lane;
    int nb = (pb & ~15) | ((pb & 3) << 2) | ((pb & 15) >> 2);
    if (pa < padded) pw[base + na] = packvw(ea.x, wa * scale);
    if (pb < padded) pw[base + nb] = packvw(eb.x, wb * scale);
}

// ---------------- propagation step over z (N x 40) ----------------
// State z stays fp32 (diagonal term + output exact); gathers read the fp16
// shadow zh (80 B/row). Wave = row; grp=L>>4, col4=L&15 (c<10 valid). Per
// chunk: one dwordx4 pw quad + 4 dwordx2 fp16 gathers + 16 fma.
template <bool LAST>
__global__ __launch_bounds__(256) void stepz_k(const float* __restrict__ zin,
    const _Float16* __restrict__ zhin, float* __restrict__ zout,
    _Float16* __restrict__ zhout, const int* __restrict__ nc,
    const unsigned int* __restrict__ pw, const float* __restrict__ db)
{
    int row  = (blockIdx.x * 256 + threadIdx.x) >> 6;
    int lane = threadIdx.x & 63;
    int grp  = lane >> 4;
    int col4 = lane & 15;
    int c9   = (col4 < 10) ? col4 : 9;
    int ch   = c9 << 2;                    // half-offset within row
    int ncv  = nc[row];                    // wave-uniform
    const unsigned int* pwrow = pw + (size_t)row * CAP_ + (grp << 2);
    f32x4 acc = {0.f, 0.f, 0.f, 0.f};
    u32x4 q = *(const u32x4*)pwrow;        // chunk 0 quad (unused if ncv==0)
    for (int c = 0; c < ncv; ++c) {
        f16x4 h0 = *(const f16x4*)(zhin + (size_t)(q[0] & 0x1FFFu) * C_ + ch);
        f16x4 h1 = *(const f16x4*)(zhin + (size_t)(q[1] & 0x1FFFu) * C_ + ch);
        f16x4 h2 = *(const f16x4*)(zhin + (size_t)(q[2] & 0x1FFFu) * C_ + ch);
        f16x4 h3 = *(const f16x4*)(zhin + (size_t)(q[3] & 0x1FFFu) * C_ + ch);
        int cn = (c + 1 < ncv) ? (c + 1) : c;            // branch-free lookahead
        u32x4 qn = *(const u32x4*)(pwrow + ((size_t)cn << 4));
        float w0 = __uint_as_float(q[0] & 0xFFFFE000u);
        float w1 = __uint_as_float(q[1] & 0xFFFFE000u);
        float w2 = __uint_as_float(q[2] & 0xFFFFE000u);
        float w3 = __uint_as_float(q[3] & 0xFFFFE000u);
        acc[0] = fmaf(w0, (float)h0[0], acc[0]); acc[1] = fmaf(w0, (float)h0[1], acc[1]);
        acc[2] = fmaf(w0, (float)h0[2], acc[2]); acc[3] = fmaf(w0, (float)h0[3], acc[3]);
        acc[0] = fmaf(w1, (float)h1[0], acc[0]); acc[1] = fmaf(w1, (float)h1[1], acc[1]);
        acc[2] = fmaf(w1, (float)h1[2], acc[2]); acc[3] = fmaf(w1, (float)h1[3], acc[3]);
        acc[0] = fmaf(w2, (float)h2[0], acc[0]); acc[1] = fmaf(w2, (float)h2[1], acc[1]);
        acc[2] = fmaf(w2, (float)h2[2], acc[2]); acc[3] = fmaf(w2, (float)h2[3], acc[3]);
        acc[0] = fmaf(w3, (float)h3[0], acc[0]); acc[1] = fmaf(w3, (float)h3[1], acc[1]);
        acc[2] = fmaf(w3, (float)h3[2], acc[2]); acc[3] = fmaf(w3, (float)h3[3], acc[3]);
        q = qn;
    }
    acc[0] += __shfl_xor(acc[0], 16); acc[1] += __shfl_xor(acc[1], 16);
    acc[2] += __shfl_xor(acc[2], 16); acc[3] += __shfl_xor(acc[3], 16);
    acc[0] += __shfl_xor(acc[0], 32); acc[1] += __shfl_xor(acc[1], 32);
    acc[2] += __shfl_xor(acc[2], 32); acc[3] += __shfl_xor(acc[3], 32);
    if (grp == 0 && col4 < 10) {
        f32x4 xr = *(const f32x4*)(zin + (size_t)row * C_ + (col4 << 2));
        f32x4 r;
        r[0] = fmaf(1.0f - TAU_, xr[0], acc[0]);
        r[1] = fmaf(1.0f - TAU_, xr[1], acc[1]);
        r[2] = fmaf(1.0f - TAU_, xr[2], acc[2]);
        r[3] = fmaf(1.0f - TAU_, xr[3], acc[3]);
        if (LAST) {
            f32x4 bb = *(const f32x4*)(db + (col4 << 2));
            r[0] += bb[0]; r[1] += bb[1]; r[2] += bb[2]; r[3] += bb[3];
        }
        *(f32x4*)(zout + (size_t)row * C_ + (col4 << 2)) = r;
        if (!LAST) {
            f16x4 rh;
            rh[0] = (_Float16)r[0]; rh[1] = (_Float16)r[1];
            rh[2] = (_Float16)r[2]; rh[3] = (_Float16)r[3];
            *(f16x4*)(zhout + (size_t)row * C_ + (col4 << 2)) = rh;
        }
    }
}

extern "C" void kernel_launch(void* const* d_in, const int* in_sizes, int n_in,
                              void* d_out, int out_size, void* d_ws, size_t ws_size,
                              hipStream_t stream)
{
    const float* x_in  = (const float*)d_in[0];
    const float* enc_w = (const float*)d_in[1];
    const float* enc_b = (const float*)d_in[2];
    const float* wk_w  = (const float*)d_in[3];
    const float* wk_b  = (const float*)d_in[4];
    const float* wq_w  = (const float*)d_in[5];
    const float* wq_b  = (const float*)d_in[6];
    const float* dec_w = (const float*)d_in[7];
    const float* dec_b = (const float*)d_in[8];
    const int2*  edges = (const int2*)d_in[9];
    const int E = in_sizes[9] / 2;   // 262144
    float* out = (float*)d_out;

    char* ws = (char*)d_ws;
    float*        za   = (float*)(ws + 0);                    // 1.31 MB (+pad)
    float*        zb   = (float*)(ws + (2u << 20));           // 1.31 MB (+pad)
    float*        kx   = (float*)(ws + (4u << 20));           // 2 MB
    float*        qx   = (float*)(ws + (6u << 20));           // 2 MB
    int2*         bvw  = (int2*) (ws + (8u << 20));           // 8 MB raw buckets
    unsigned int* pw   = (unsigned int*)(ws + (16u << 20));   // 4 MB packed
    int*          fill = (int*)  (ws + (20u << 20));          // 32 KB
    int*          nc   = (int*)  (ws + (20u << 20) + (64u << 10)); // 32 KB
    _Float16*     zha  = (_Float16*)(ws + (21u << 20));       // 640 KB
    _Float16*     zhb  = (_Float16*)(ws + (22u << 20));       // 640 KB

    hipMemsetAsync(fill, 0, N_ * sizeof(int), stream);

    front_k<<<N_ / 16, 256, 0, stream>>>(x_in, enc_w, enc_b, wk_w, wk_b,
                                         wq_w, wq_b, dec_w, kx, qx, za, zha);
    score_place_k<<<(E * 8 + 255) / 256, 256, 0, stream>>>(edges, kx, qx, fill, bvw, E);
    dedup_k<<<N_ / 4, 256, 0, stream>>>(fill, bvw, pw, nc);

    float*    zi  = za;
    _Float16* zhi = zha;
    for (int s = 0; s < STEPS_ - 1; ++s) {
        float*    zo  = (zi == za) ? zb : za;
        _Float16* zho = (zhi == zha) ? zhb : zha;
        stepz_k<false><<<N_ / 4, 256, 0, stream>>>(zi, zhi, zo, zho, nc, pw, dec_b);
        zi = zo; zhi = zho;
    }
    stepz_k<true><<<N_ / 4, 256, 0, stream>>>(zi, zhi, out, nullptr, nc, pw, dec_b);
}